// Round 5
// baseline (91.916 us; speedup 1.0000x reference)
//
#include <hip/hip_runtime.h>
#include <math.h>

// ExpLogDiceLoss: N x 32 fp32 scores, int32 labels -> scalar loss.
//
// loss_c = pow( log((counts_c + npr_sum_c) / (2 * ni_sum_c)), 0.3 ) for present c
// out = sum_c loss_c / n_present
// where npr_sum_c = sum_rows softmax(score[row])[c]
//       ni_sum_c  = sum_{rows: label==c} softmax(score[row])[c]
//
// Single fused kernel: per-block partials -> u64 fixed-point device atomics
// (deterministic: integer adds commute), last block (ticket) computes the
// scalar epilogue. ws[0..95] = {npr[32], ni[32], cnt[32]} as u64, ws[96] = ticket.

#define P1_BLOCKS 2048
#define P1_THREADS 256
#define FIX_SCALE 67108864.0f        // 2^26
#define FIX_INV   1.4901161193847656e-8f  // 2^-26

__global__ __launch_bounds__(P1_THREADS) void eld_fused(
    const float* __restrict__ score, const int* __restrict__ label,
    unsigned long long* __restrict__ acc,   // [96]
    unsigned int* __restrict__ ticket,      // [1]
    float* __restrict__ out,
    int nrows, int ngroups, int nblk)
{
    const int tid   = threadIdx.x;
    const int q     = tid & 7;     // column quarter: classes [4q, 4q+4)
    const int rslot = tid >> 3;    // row slot within a 32-row group
    const int cbase = q << 2;

    float a_npr0 = 0.f, a_npr1 = 0.f, a_npr2 = 0.f, a_npr3 = 0.f;
    float a_ni0  = 0.f, a_ni1  = 0.f, a_ni2  = 0.f, a_ni3  = 0.f;
    float a_c0   = 0.f, a_c1   = 0.f, a_c2   = 0.f, a_c3   = 0.f;

    for (int g = blockIdx.x; g < ngroups; g += gridDim.x) {
        const int row = g * 32 + rslot;
        if (row < nrows) {
            const float4 v = reinterpret_cast<const float4*>(score)[row * 8 + q];
            // row max across 32 classes (8 lanes x 4 elems)
            float m = fmaxf(fmaxf(v.x, v.y), fmaxf(v.z, v.w));
            m = fmaxf(m, __shfl_xor(m, 1));
            m = fmaxf(m, __shfl_xor(m, 2));
            m = fmaxf(m, __shfl_xor(m, 4));
            const float e0 = __expf(v.x - m);
            const float e1 = __expf(v.y - m);
            const float e2 = __expf(v.z - m);
            const float e3 = __expf(v.w - m);
            float s = (e0 + e1) + (e2 + e3);
            s += __shfl_xor(s, 1);
            s += __shfl_xor(s, 2);
            s += __shfl_xor(s, 4);
            const float inv = __builtin_amdgcn_rcpf(s);  // s >= 1, ~1 ulp
            const float p0 = e0 * inv, p1 = e1 * inv, p2 = e2 * inv, p3 = e3 * inv;
            a_npr0 += p0; a_npr1 += p1; a_npr2 += p2; a_npr3 += p3;
            const int lab = label[row];
            // static-indexed predicated accumulate (avoid runtime-indexed arrays)
            if (lab == cbase + 0) { a_ni0 += p0; a_c0 += 1.f; }
            if (lab == cbase + 1) { a_ni1 += p1; a_c1 += 1.f; }
            if (lab == cbase + 2) { a_ni2 += p2; a_c2 += 1.f; }
            if (lab == cbase + 3) { a_ni3 += p3; a_c3 += 1.f; }
        }
    }

    // reduce across the 8 row-slots of each wave (lanes with equal (lane&7))
#pragma unroll
    for (int off = 8; off < 64; off <<= 1) {
        a_npr0 += __shfl_xor(a_npr0, off);
        a_npr1 += __shfl_xor(a_npr1, off);
        a_npr2 += __shfl_xor(a_npr2, off);
        a_npr3 += __shfl_xor(a_npr3, off);
        a_ni0  += __shfl_xor(a_ni0,  off);
        a_ni1  += __shfl_xor(a_ni1,  off);
        a_ni2  += __shfl_xor(a_ni2,  off);
        a_ni3  += __shfl_xor(a_ni3,  off);
        a_c0   += __shfl_xor(a_c0,   off);
        a_c1   += __shfl_xor(a_c1,   off);
        a_c2   += __shfl_xor(a_c2,   off);
        a_c3   += __shfl_xor(a_c3,   off);
    }

    __shared__ float lds[3][4][32];
    const int wave = tid >> 6;
    const int lane = tid & 63;
    if (lane < 8) {
        lds[0][wave][lane * 4 + 0] = a_npr0;
        lds[0][wave][lane * 4 + 1] = a_npr1;
        lds[0][wave][lane * 4 + 2] = a_npr2;
        lds[0][wave][lane * 4 + 3] = a_npr3;
        lds[1][wave][lane * 4 + 0] = a_ni0;
        lds[1][wave][lane * 4 + 1] = a_ni1;
        lds[1][wave][lane * 4 + 2] = a_ni2;
        lds[1][wave][lane * 4 + 3] = a_ni3;
        lds[2][wave][lane * 4 + 0] = a_c0;
        lds[2][wave][lane * 4 + 1] = a_c1;
        lds[2][wave][lane * 4 + 2] = a_c2;
        lds[2][wave][lane * 4 + 3] = a_c3;
    }
    __syncthreads();
    if (tid < 32) {
        float n = 0.f, i2 = 0.f, k = 0.f;
#pragma unroll
        for (int w = 0; w < 4; ++w) {
            n  += lds[0][w][tid];
            i2 += lds[1][w][tid];
            k  += lds[2][w][tid];
        }
        // deterministic fixed-point accumulate (values >= 0)
        atomicAdd(&acc[tid],      (unsigned long long)(n  * FIX_SCALE + 0.5f));
        atomicAdd(&acc[32 + tid], (unsigned long long)(i2 * FIX_SCALE + 0.5f));
        atomicAdd(&acc[64 + tid], (unsigned long long)(k + 0.5f));
    }
    __syncthreads();   // drains the atomics (vmcnt) before the ticket

    __shared__ unsigned int is_last;
    if (tid == 0) {
        __threadfence();
        unsigned int old = atomicAdd(ticket, 1u);
        is_last = (old == (unsigned int)(nblk - 1)) ? 1u : 0u;
    }
    __syncthreads();
    if (!is_last) return;

    // ---- last block: epilogue over 32 classes ----
    __shared__ float l_loss[32], l_pres[32];
    if (tid < 32) {
        unsigned long long un = __hip_atomic_load(&acc[tid],      __ATOMIC_RELAXED, __HIP_MEMORY_SCOPE_AGENT);
        unsigned long long ui = __hip_atomic_load(&acc[32 + tid], __ATOMIC_RELAXED, __HIP_MEMORY_SCOPE_AGENT);
        unsigned long long uk = __hip_atomic_load(&acc[64 + tid], __ATOMIC_RELAXED, __HIP_MEMORY_SCOPE_AGENT);
        float loss = 0.f, pres = 0.f;
        if (uk > 0ull) {
            const float N_ = (float)((double)un * (double)FIX_INV);
            const float I  = (float)((double)ui * (double)FIX_INV);
            const float K  = (float)uk;
            float nld = logf((K + N_) / (2.f * I));   // >= 0 by construction
            nld = fmaxf(nld, 0.f);
            loss = powf(nld, 0.3f);
            pres = 1.f;
        }
        l_loss[tid] = loss;
        l_pres[tid] = pres;
    }
    __syncthreads();
    if (tid == 0) {
        float sum = 0.f, np = 0.f;
#pragma unroll
        for (int c2 = 0; c2 < 32; ++c2) { sum += l_loss[c2]; np += l_pres[c2]; }
        out[0] = sum / np;  // LOSS_WEIGHT = 1
    }
}

extern "C" void kernel_launch(void* const* d_in, const int* in_sizes, int n_in,
                              void* d_out, int out_size, void* d_ws, size_t ws_size,
                              hipStream_t stream) {
    const float* score = (const float*)d_in[0];
    const int*   label = (const int*)d_in[1];
    float* out = (float*)d_out;

    const int nrows = in_sizes[0] / 32;
    const int ngroups = (nrows + 31) / 32;

    int nblk = P1_BLOCKS;
    if (nblk > ngroups) nblk = ngroups;

    unsigned long long* acc = (unsigned long long*)d_ws;   // [96]
    unsigned int* ticket = (unsigned int*)(acc + 96);      // [1]

    // zero accumulators + ticket every call (ws is poisoned 0xAA before timing)
    hipMemsetAsync(d_ws, 0, 96 * sizeof(unsigned long long) + sizeof(unsigned int),
                   stream);

    eld_fused<<<nblk, P1_THREADS, 0, stream>>>(score, label, acc, ticket, out,
                                               nrows, ngroups, nblk);
}

// Round 6
// 33.851 us; speedup vs baseline: 2.7153x; 2.7153x over previous
//
#include <hip/hip_runtime.h>
#include <math.h>

// ExpLogDiceLoss: N x 32 fp32 scores, int32 labels -> scalar loss.
//
// loss_c = pow( log((counts_c + npr_sum_c) / (2 * ni_sum_c)), 0.3 ) for present c
// out = sum_c loss_c / n_present
// where npr_sum_c = sum_rows softmax(score[row])[c]
//       ni_sum_c  = sum_{rows: label==c} softmax(score[row])[c]
//
// Two deterministic passes (no atomics — R5 showed contended device-scope
// atomics on a 768B region cost ~100us). Pass1: 512 blocks x 1024 threads
// (8192 waves = 32/CU), 8 threads per row, per-block reduce -> 196 KB partials.
// Pass2: one 1024-thread block tree-reduces 512 partials + scalar epilogue.

#define P1_BLOCKS 512
#define P1_THREADS 1024

__global__ __launch_bounds__(P1_THREADS) void eld_pass1(
    const float* __restrict__ score, const int* __restrict__ label,
    float* __restrict__ p_npr, float* __restrict__ p_ni, float* __restrict__ p_cnt,
    int nrows, int ngroups)
{
    const int tid   = threadIdx.x;
    const int q     = tid & 7;     // column quarter: classes [4q, 4q+4)
    const int rslot = tid >> 3;    // row slot within a 128-row group
    const int cbase = q << 2;

    float a_npr0 = 0.f, a_npr1 = 0.f, a_npr2 = 0.f, a_npr3 = 0.f;
    float a_ni0  = 0.f, a_ni1  = 0.f, a_ni2  = 0.f, a_ni3  = 0.f;
    float a_c0   = 0.f, a_c1   = 0.f, a_c2   = 0.f, a_c3   = 0.f;

    for (int g = blockIdx.x; g < ngroups; g += gridDim.x) {
        const int row = g * 128 + rslot;
        if (row < nrows) {
            const float4 v = reinterpret_cast<const float4*>(score)[row * 8 + q];
            // row max across 32 classes (8 lanes x 4 elems)
            float m = fmaxf(fmaxf(v.x, v.y), fmaxf(v.z, v.w));
            m = fmaxf(m, __shfl_xor(m, 1));
            m = fmaxf(m, __shfl_xor(m, 2));
            m = fmaxf(m, __shfl_xor(m, 4));
            const float e0 = __expf(v.x - m);
            const float e1 = __expf(v.y - m);
            const float e2 = __expf(v.z - m);
            const float e3 = __expf(v.w - m);
            float s = (e0 + e1) + (e2 + e3);
            s += __shfl_xor(s, 1);
            s += __shfl_xor(s, 2);
            s += __shfl_xor(s, 4);
            const float inv = __builtin_amdgcn_rcpf(s);  // s >= 1, ~1 ulp
            const float p0 = e0 * inv, p1 = e1 * inv, p2 = e2 * inv, p3 = e3 * inv;
            a_npr0 += p0; a_npr1 += p1; a_npr2 += p2; a_npr3 += p3;
            const int lab = label[row];
            // static-indexed predicated accumulate (avoid runtime-indexed arrays)
            if (lab == cbase + 0) { a_ni0 += p0; a_c0 += 1.f; }
            if (lab == cbase + 1) { a_ni1 += p1; a_c1 += 1.f; }
            if (lab == cbase + 2) { a_ni2 += p2; a_c2 += 1.f; }
            if (lab == cbase + 3) { a_ni3 += p3; a_c3 += 1.f; }
        }
    }

    // reduce across the 8 row-slots of each wave (lanes with equal (lane&7))
#pragma unroll
    for (int off = 8; off < 64; off <<= 1) {
        a_npr0 += __shfl_xor(a_npr0, off);
        a_npr1 += __shfl_xor(a_npr1, off);
        a_npr2 += __shfl_xor(a_npr2, off);
        a_npr3 += __shfl_xor(a_npr3, off);
        a_ni0  += __shfl_xor(a_ni0,  off);
        a_ni1  += __shfl_xor(a_ni1,  off);
        a_ni2  += __shfl_xor(a_ni2,  off);
        a_ni3  += __shfl_xor(a_ni3,  off);
        a_c0   += __shfl_xor(a_c0,   off);
        a_c1   += __shfl_xor(a_c1,   off);
        a_c2   += __shfl_xor(a_c2,   off);
        a_c3   += __shfl_xor(a_c3,   off);
    }

    __shared__ float lds[3][16][32];
    const int wave = tid >> 6;
    const int lane = tid & 63;
    if (lane < 8) {
        lds[0][wave][lane * 4 + 0] = a_npr0;
        lds[0][wave][lane * 4 + 1] = a_npr1;
        lds[0][wave][lane * 4 + 2] = a_npr2;
        lds[0][wave][lane * 4 + 3] = a_npr3;
        lds[1][wave][lane * 4 + 0] = a_ni0;
        lds[1][wave][lane * 4 + 1] = a_ni1;
        lds[1][wave][lane * 4 + 2] = a_ni2;
        lds[1][wave][lane * 4 + 3] = a_ni3;
        lds[2][wave][lane * 4 + 0] = a_c0;
        lds[2][wave][lane * 4 + 1] = a_c1;
        lds[2][wave][lane * 4 + 2] = a_c2;
        lds[2][wave][lane * 4 + 3] = a_c3;
    }
    __syncthreads();
    if (tid < 32) {
        float n = 0.f, i2 = 0.f, k = 0.f;
#pragma unroll
        for (int w = 0; w < 16; ++w) {
            n  += lds[0][w][tid];
            i2 += lds[1][w][tid];
            k  += lds[2][w][tid];
        }
        p_npr[blockIdx.x * 32 + tid] = n;
        p_ni [blockIdx.x * 32 + tid] = i2;
        p_cnt[blockIdx.x * 32 + tid] = k;
    }
}

// Single block, 1024 threads (16 waves): 32 slots x 32 classes.
__global__ __launch_bounds__(1024) void eld_pass2(
    const float* __restrict__ p_npr, const float* __restrict__ p_ni,
    const float* __restrict__ p_cnt, float* __restrict__ out, int nblk)
{
    __shared__ float l_npr[32][32], l_ni[32][32], l_cnt[32][32];
    __shared__ float l_loss[32], l_pres[32];
    const int tid = threadIdx.x;
    const int c = tid & 31;
    const int s = tid >> 5;  // 0..31
    float n = 0.f, i2 = 0.f, k = 0.f;
#pragma unroll 4
    for (int b = s; b < nblk; b += 32) {
        n  += p_npr[b * 32 + c];
        i2 += p_ni [b * 32 + c];
        k  += p_cnt[b * 32 + c];
    }
    l_npr[s][c] = n; l_ni[s][c] = i2; l_cnt[s][c] = k;
    __syncthreads();
    if (tid < 32) {
        float N_ = 0.f, I = 0.f, K = 0.f;
#pragma unroll
        for (int w = 0; w < 32; ++w) { N_ += l_npr[w][tid]; I += l_ni[w][tid]; K += l_cnt[w][tid]; }
        float loss = 0.f, pres = 0.f;
        if (K > 0.f) {
            // neg_log_dice = log((K + npr_sum) / (2*ni_sum)) >= 0
            float nld = logf((K + N_) / (2.f * I));
            nld = fmaxf(nld, 0.f);
            loss = powf(nld, 0.3f);
            pres = 1.f;
        }
        l_loss[tid] = loss;
        l_pres[tid] = pres;
    }
    __syncthreads();
    if (tid == 0) {
        float sum = 0.f, np = 0.f;
#pragma unroll
        for (int c2 = 0; c2 < 32; ++c2) { sum += l_loss[c2]; np += l_pres[c2]; }
        out[0] = sum / np;  // LOSS_WEIGHT = 1
    }
}

extern "C" void kernel_launch(void* const* d_in, const int* in_sizes, int n_in,
                              void* d_out, int out_size, void* d_ws, size_t ws_size,
                              hipStream_t stream) {
    const float* score = (const float*)d_in[0];
    const int*   label = (const int*)d_in[1];
    float* out = (float*)d_out;

    const int nrows = in_sizes[0] / 32;
    const int ngroups = (nrows + 127) / 128;

    int nblk = P1_BLOCKS;
    if (nblk > ngroups) nblk = ngroups;

    float* p_npr = (float*)d_ws;
    float* p_ni  = p_npr + (size_t)nblk * 32;
    float* p_cnt = p_ni  + (size_t)nblk * 32;

    eld_pass1<<<nblk, P1_THREADS, 0, stream>>>(score, label, p_npr, p_ni, p_cnt,
                                               nrows, ngroups);
    eld_pass2<<<1, 1024, 0, stream>>>(p_npr, p_ni, p_cnt, out, nblk);
}